// Round 1
// baseline (308.255 us; speedup 1.0000x reference)
//
#include <hip/hip_runtime.h>
#include <hip/hip_bf16.h>

// Problem constants (fixed by setup_inputs):
//   B=4, N_down=16384, N_up=65536, C_down=256, C_up=128, C_out=128
// Key restructure vs previous version: MLP1 commutes with the gather.
//   y = leaky(x_down @ W_lin + b_lin)  computed ONCE per down-row (65536 rows,
//   4x fewer GEMM1 FLOPs than per-up-row), stored bf16 (identical rounding to
//   the old kernel's x_lin->concat-tile conversion). The hot kernel then
//   gathers 256B bf16 rows (L2/L3-resident, half the bytes) and runs a single
//   stage -> sync -> GEMM2 -> store pipeline.
constexpr int N_DOWN = 16384;
constexpr int N_UP   = 65536;
constexpr int BATCH  = 4;
constexpr int M_BLK  = 64;     // rows per block
constexpr int TS     = 264;    // LDS row stride (bf16): 256+8 pad, 528B rows (16B-aligned)

typedef __attribute__((ext_vector_type(8))) short short8;   // 8 x bf16 MFMA A/B frag
typedef __attribute__((ext_vector_type(4))) float f32x4;    // MFMA C/D frag

static __device__ inline unsigned short f2b(float f) {
  __hip_bfloat16 h = __float2bfloat16(f);
  return __builtin_bit_cast(unsigned short, h);
}
// fp32x4 -> bf16x4, single 8B LDS store
static __device__ inline void cvt_store4(__hip_bfloat16* dst, float4 v) {
  ushort4 s;
  s.x = f2b(v.x); s.y = f2b(v.y); s.z = f2b(v.z); s.w = f2b(v.w);
  *(ushort4*)dst = s;
}

// ---------------------------------------------------------------------------
// Repack W_lin / W_fus ([K=256][N=128] row-major fp32) into bf16 MFMA
// B-fragment order: chunk t = w*4096 + kk*512 + strip*64 + lane holds
//   val[j] = W[kk*32 + (lane>>4)*8 + j][strip*16 + (lane&15)]
// so each B-frag is ONE contiguous 16B load in the consumers.
// ---------------------------------------------------------------------------
__global__ void repack_w(const float* __restrict__ Wl,
                         const float* __restrict__ Wf,
                         __hip_bfloat16* __restrict__ pack) {
  int t = blockIdx.x * 256 + threadIdx.x;          // 0 .. 8191
  if (t >= 8192) return;
  int lane  = t & 63;
  int strip = (t >> 6) & 7;
  int kk    = (t >> 9) & 7;
  int w     = t >> 12;
  const float* W = w ? Wf : Wl;
  int q = lane >> 4;
  int l = lane & 15;
  int c = strip * 16 + l;
  short8 vals;
#pragma unroll
  for (int j = 0; j < 8; ++j) {
    int k = kk * 32 + q * 8 + j;
    vals[j] = (short)f2b(W[k * 128 + c]);
  }
  *(short8*)(pack + (size_t)t * 8) = vals;
}

// ---------------------------------------------------------------------------
// Kernel A: y[r, :] = leaky(x_down[r, :] @ W_lin + b_lin), bf16 out.
// Sequential rows (no gather), 64-row tiles, wave w owns 16-col strip.
// 65536 rows total -> 1024 blocks. ~84 MB traffic, ~15 us.
// ---------------------------------------------------------------------------
__global__ __launch_bounds__(512, 8)
void mlp1_down(const float* __restrict__ x_down,
               const float* __restrict__ b_lin,
               const __hip_bfloat16* __restrict__ pack,
               __hip_bfloat16* __restrict__ y) {
  __shared__ __hip_bfloat16 T[M_BLK * TS];

  const int tid  = threadIdx.x;
  const int wave = tid >> 6;
  const int lane = tid & 63;
  const int q    = lane >> 4;
  const int l    = lane & 15;
  const int m0   = blockIdx.x * M_BLK;   // flat row over BATCH*N_DOWN

  // stage x_down tile (coalesced: 8 lanes x 16B per 128B line, fp32->bf16)
  {
    const int lr = tid >> 3;
    const int s8 = tid & 7;
    const float* src = x_down + (size_t)(m0 + lr) * 256;
    __hip_bfloat16* dst = T + lr * TS;
#pragma unroll
    for (int j = 0; j < 8; ++j) {
      int c4 = j * 8 + s8;
      float4 v = *(const float4*)(src + c4 * 4);
      cvt_store4(dst + c4 * 4, v);
    }
  }

  short8 B1[8];
#pragma unroll
  for (int kk = 0; kk < 8; ++kk)
    B1[kk] = *(const short8*)(pack + (size_t)((kk * 8 + wave) * 64 + lane) * 8);
  const float bias1 = b_lin[wave * 16 + l];

  __syncthreads();

  f32x4 acc[4];
#pragma unroll
  for (int rg = 0; rg < 4; ++rg) acc[rg] = f32x4{0.f, 0.f, 0.f, 0.f};
#pragma unroll
  for (int kk = 0; kk < 8; ++kk) {
#pragma unroll
    for (int rg = 0; rg < 4; ++rg) {
      short8 a = *(const short8*)(T + (rg * 16 + l) * TS + kk * 32 + q * 8);
      acc[rg] = __builtin_amdgcn_mfma_f32_16x16x32_bf16(a, B1[kk], acc[rg], 0, 0, 0);
    }
  }

  // epilogue: bias + leaky -> bf16 y (16 lanes = 32B contiguous runs)
#pragma unroll
  for (int rg = 0; rg < 4; ++rg) {
#pragma unroll
    for (int i = 0; i < 4; ++i) {
      float v = acc[rg][i] + bias1;
      v = (v >= 0.f) ? v : 0.1f * v;
      y[(size_t)(m0 + rg * 16 + q * 4 + i) * 128 + wave * 16 + l] = __float2bfloat16(v);
    }
  }
}

// ---------------------------------------------------------------------------
// Kernel B: out = leaky(concat(x_up, gather(y)) @ W_fus + b_fus).
// Single-phase pipeline: [gather y (bf16 memcpy) | x_up cvt | B2 frags]
//   -> sync -> GEMM2 -> store. One barrier, 32 MFMA/wave; overlap comes from
//   4 blocks/CU (LDS 33.8 KB).
// ---------------------------------------------------------------------------
__global__ __launch_bounds__(512, 8)
void fused_cat(const float* __restrict__ x_up,
               const int* __restrict__ up_idx,
               const __hip_bfloat16* __restrict__ y,
               const float* __restrict__ b_fus,
               const __hip_bfloat16* __restrict__ pack,
               float* __restrict__ out) {
  __shared__ __hip_bfloat16 T[M_BLK * TS];

  const int tid  = threadIdx.x;
  const int wave = tid >> 6;
  const int lane = tid & 63;
  const int q    = lane >> 4;
  const int l    = lane & 15;
  const int m0   = blockIdx.x * M_BLK;    // flat row over BATCH*N_UP
  const int b    = m0 >> 16;              // / N_UP

  // gather y rows -> T cols 128..255 (issued first: longest dependence chain;
  // 16 threads x 16B = one 256B row, already bf16 so pure copy)
#pragma unroll
  for (int j = 0; j < 2; ++j) {
    int f = j * 512 + tid;
    int r = f >> 4;
    int c = f & 15;
    int gi = up_idx[m0 + r];
    const __hip_bfloat16* src = y + ((size_t)b * N_DOWN + gi) * 128 + c * 8;
    *(short8*)(T + r * TS + 128 + c * 8) = *(const short8*)src;
  }

  // x_up -> T cols 0..127 (coalesced streaming, fp32 -> bf16)
#pragma unroll
  for (int j = 0; j < 4; ++j) {
    int f = j * 512 + tid;
    int r = f >> 5;
    int c4 = f & 31;
    float4 v = *(const float4*)(x_up + (size_t)(m0 + r) * 128 + c4 * 4);
    cvt_store4(T + r * TS + c4 * 4, v);
  }

  short8 B2[8];
#pragma unroll
  for (int kk = 0; kk < 8; ++kk)
    B2[kk] = *(const short8*)(pack + (size_t)(4096 + (kk * 8 + wave) * 64 + lane) * 8);
  const float bias2 = b_fus[wave * 16 + l];

  __syncthreads();

  f32x4 acc[4];
#pragma unroll
  for (int rg = 0; rg < 4; ++rg) acc[rg] = f32x4{0.f, 0.f, 0.f, 0.f};
#pragma unroll
  for (int kk = 0; kk < 8; ++kk) {
#pragma unroll
    for (int rg = 0; rg < 4; ++rg) {
      short8 a = *(const short8*)(T + (rg * 16 + l) * TS + kk * 32 + q * 8);
      acc[rg] = __builtin_amdgcn_mfma_f32_16x16x32_bf16(a, B2[kk], acc[rg], 0, 0, 0);
    }
  }

  // epilogue: bias + leaky -> fp32 out (16 lanes = 64B runs)
#pragma unroll
  for (int rg = 0; rg < 4; ++rg) {
#pragma unroll
    for (int i = 0; i < 4; ++i) {
      float v = acc[rg][i] + bias2;
      v = (v >= 0.f) ? v : 0.1f * v;
      out[(size_t)(m0 + rg * 16 + q * 4 + i) * 128 + wave * 16 + l] = v;
    }
  }
}

extern "C" void kernel_launch(void* const* d_in, const int* in_sizes, int n_in,
                              void* d_out, int out_size, void* d_ws, size_t ws_size,
                              hipStream_t stream) {
  const float* x_down = (const float*)d_in[0];
  const float* x_up   = (const float*)d_in[1];
  const int*   up_idx = (const int*)d_in[2];
  const float* W_lin  = (const float*)d_in[3];
  const float* b_lin  = (const float*)d_in[4];
  const float* W_fus  = (const float*)d_in[5];
  const float* b_fus  = (const float*)d_in[6];
  float* out = (float*)d_out;

  // workspace layout: [0, 128 KiB) weight pack, [128 KiB, +16 MiB) y (bf16)
  __hip_bfloat16* pack = (__hip_bfloat16*)d_ws;
  __hip_bfloat16* y    = (__hip_bfloat16*)((char*)d_ws + 131072);

  repack_w<<<32, 256, 0, stream>>>(W_lin, W_fus, pack);
  mlp1_down<<<(BATCH * N_DOWN) / M_BLK, 512, 0, stream>>>(x_down, b_lin, pack, y);
  fused_cat<<<(BATCH * N_UP) / M_BLK, 512, 0, stream>>>(x_up, up_idx, y, b_fus, pack, out);
}

// Round 2
// 302.165 us; speedup vs baseline: 1.0202x; 1.0202x over previous
//
#include <hip/hip_runtime.h>
#include <hip/hip_bf16.h>

// Problem constants (fixed by setup_inputs):
//   B=4, N_down=16384, N_up=65536, C_down=256, C_up=128, C_out=128
// Structure: y = leaky(x_down @ W_lin + b_lin) computed once per down-row
// (mlp1_down, bf16 out), then fused_cat gathers y + streams x_up through a
// PERSISTENT double-buffered LDS pipeline:
//   per iter: issue loads(t+1) -> GEMM(t) -> cvt+ds_write(t+1) -> barrier
// with idx prefetched two tiles ahead so the gather issues immediately.
constexpr int N_DOWN = 16384;
constexpr int N_UP   = 65536;
constexpr int BATCH  = 4;
constexpr int M_BLK  = 64;     // rows per tile
constexpr int TS     = 264;    // LDS row stride for mlp1_down (256+8 pad)
constexpr int ITERS  = 4;      // tiles per persistent block (fused_cat)
constexpr int GRID_C = (BATCH * N_UP) / M_BLK / ITERS;   // 512 blocks

typedef __attribute__((ext_vector_type(8))) short short8;   // 8 x bf16 MFMA A/B frag
typedef __attribute__((ext_vector_type(4))) float f32x4;    // MFMA C/D frag

static __device__ inline unsigned short f2b(float f) {
  __hip_bfloat16 h = __float2bfloat16(f);
  return __builtin_bit_cast(unsigned short, h);
}
// fp32x4 -> bf16x4, single 8B LDS store
static __device__ inline void cvt_store4(__hip_bfloat16* dst, float4 v) {
  ushort4 s;
  s.x = f2b(v.x); s.y = f2b(v.y); s.z = f2b(v.z); s.w = f2b(v.w);
  *(ushort4*)dst = s;
}

// ---------------------------------------------------------------------------
// Repack W_lin / W_fus ([K=256][N=128] row-major fp32) into bf16 MFMA
// B-fragment order: chunk t = w*4096 + kk*512 + strip*64 + lane holds
//   val[j] = W[kk*32 + (lane>>4)*8 + j][strip*16 + (lane&15)]
// ---------------------------------------------------------------------------
__global__ void repack_w(const float* __restrict__ Wl,
                         const float* __restrict__ Wf,
                         __hip_bfloat16* __restrict__ pack) {
  int t = blockIdx.x * 256 + threadIdx.x;          // 0 .. 8191
  if (t >= 8192) return;
  int lane  = t & 63;
  int strip = (t >> 6) & 7;
  int kk    = (t >> 9) & 7;
  int w     = t >> 12;
  const float* W = w ? Wf : Wl;
  int q = lane >> 4;
  int l = lane & 15;
  int c = strip * 16 + l;
  short8 vals;
#pragma unroll
  for (int j = 0; j < 8; ++j) {
    int k = kk * 32 + q * 8 + j;
    vals[j] = (short)f2b(W[k * 128 + c]);
  }
  *(short8*)(pack + (size_t)t * 8) = vals;
}

// ---------------------------------------------------------------------------
// Kernel A: y[r, :] = leaky(x_down[r, :] @ W_lin + b_lin), bf16 out.
// (unchanged from previous round to isolate the fused_cat change)
// ---------------------------------------------------------------------------
__global__ __launch_bounds__(512, 8)
void mlp1_down(const float* __restrict__ x_down,
               const float* __restrict__ b_lin,
               const __hip_bfloat16* __restrict__ pack,
               __hip_bfloat16* __restrict__ y) {
  __shared__ __hip_bfloat16 T[M_BLK * TS];

  const int tid  = threadIdx.x;
  const int wave = tid >> 6;
  const int lane = tid & 63;
  const int q    = lane >> 4;
  const int l    = lane & 15;
  const int m0   = blockIdx.x * M_BLK;   // flat row over BATCH*N_DOWN

  {
    const int lr = tid >> 3;
    const int s8 = tid & 7;
    const float* src = x_down + (size_t)(m0 + lr) * 256;
    __hip_bfloat16* dst = T + lr * TS;
#pragma unroll
    for (int j = 0; j < 8; ++j) {
      int c4 = j * 8 + s8;
      float4 v = *(const float4*)(src + c4 * 4);
      cvt_store4(dst + c4 * 4, v);
    }
  }

  short8 B1[8];
#pragma unroll
  for (int kk = 0; kk < 8; ++kk)
    B1[kk] = *(const short8*)(pack + (size_t)((kk * 8 + wave) * 64 + lane) * 8);
  const float bias1 = b_lin[wave * 16 + l];

  __syncthreads();

  f32x4 acc[4];
#pragma unroll
  for (int rg = 0; rg < 4; ++rg) acc[rg] = f32x4{0.f, 0.f, 0.f, 0.f};
#pragma unroll
  for (int kk = 0; kk < 8; ++kk) {
#pragma unroll
    for (int rg = 0; rg < 4; ++rg) {
      short8 a = *(const short8*)(T + (rg * 16 + l) * TS + kk * 32 + q * 8);
      acc[rg] = __builtin_amdgcn_mfma_f32_16x16x32_bf16(a, B1[kk], acc[rg], 0, 0, 0);
    }
  }

#pragma unroll
  for (int rg = 0; rg < 4; ++rg) {
#pragma unroll
    for (int i = 0; i < 4; ++i) {
      float v = acc[rg][i] + bias1;
      v = (v >= 0.f) ? v : 0.1f * v;
      y[(size_t)(m0 + rg * 16 + q * 4 + i) * 128 + wave * 16 + l] = __float2bfloat16(v);
    }
  }
}

// ---------------------------------------------------------------------------
// Kernel B: out = leaky(concat(x_up, gather(y)) @ W_fus + b_fus).
// Persistent double-buffered pipeline, 512 blocks x 4 tiles.
// LDS: 2 x [64 rows x 512B], XOR-swizzled (byte ^= (row&7)<<4) to keep
// ds_read_b128 A-frag reads bank-conflict-free without padding.
// ---------------------------------------------------------------------------
__global__ __launch_bounds__(512, 4)
void fused_cat(const float* __restrict__ x_up,
               const int* __restrict__ up_idx,
               const __hip_bfloat16* __restrict__ y,
               const float* __restrict__ b_fus,
               const __hip_bfloat16* __restrict__ pack,
               float* __restrict__ out) {
  __shared__ __hip_bfloat16 T[2][M_BLK * 256];   // 2 x 32 KB

  const int tid  = threadIdx.x;
  const int wave = tid >> 6;
  const int lane = tid & 63;
  const int q    = lane >> 4;
  const int l    = lane & 15;

  const int t0 = blockIdx.x * ITERS;        // first tile of this block
  const int b  = (t0 * M_BLK) >> 16;        // batch (constant: blocks never straddle)
  const __hip_bfloat16* ybase = y + (size_t)b * N_DOWN * 128;

  // thread roles for staging
  const int gr0 = tid >> 4;                 // gather rows gr0 and gr0+32
  const int gc  = tid & 15;                 // 16B chunk within 256B y row
  const int xr  = tid >> 5;                 // x_up base row (j*16 + xr)
  const int xc  = tid & 31;                 // float4 index within 128-col row

  // swizzled byte offset within a 64x512B tile
  auto swz = [&](int row, int byte_in_row) -> int {
    return row * 512 + (byte_in_row ^ ((row & 7) << 4));
  };

  auto LOAD_IDX = [&](int t, int& ia, int& ib) {
    const int m0 = t * M_BLK;
    ia = up_idx[m0 + gr0];
    ib = up_idx[m0 + gr0 + 32];
  };
  auto LOAD_DATA = [&](int t, int ia, int ib, short8 gy[2], float4 xu[4]) {
    gy[0] = *(const short8*)(ybase + (size_t)ia * 128 + gc * 8);
    gy[1] = *(const short8*)(ybase + (size_t)ib * 128 + gc * 8);
    const int m0 = t * M_BLK;
#pragma unroll
    for (int j = 0; j < 4; ++j)
      xu[j] = *(const float4*)(x_up + (size_t)(m0 + j * 16 + xr) * 128 + xc * 4);
  };
  auto WRITE_LDS = [&](int buf, short8 gy[2], float4 xu[4]) {
    char* Tb = (char*)&T[buf][0];
    *(short8*)(Tb + swz(gr0,      256 + gc * 16)) = gy[0];
    *(short8*)(Tb + swz(gr0 + 32, 256 + gc * 16)) = gy[1];
#pragma unroll
    for (int j = 0; j < 4; ++j)
      cvt_store4((__hip_bfloat16*)(Tb + swz(j * 16 + xr, xc * 8)), xu[j]);
  };

  // B2 frags + bias: loaded once, register-resident
  short8 B2[8];
#pragma unroll
  for (int kk = 0; kk < 8; ++kk)
    B2[kk] = *(const short8*)(pack + (size_t)(4096 + (kk * 8 + wave) * 64 + lane) * 8);
  const float bias2 = b_fus[wave * 16 + l];

  auto GEMM_STORE = [&](int buf, int t) {
    const char* Tb = (const char*)&T[buf][0];
    f32x4 acc[4];
#pragma unroll
    for (int rg = 0; rg < 4; ++rg) acc[rg] = f32x4{0.f, 0.f, 0.f, 0.f};
#pragma unroll
    for (int kk = 0; kk < 8; ++kk) {
#pragma unroll
      for (int rg = 0; rg < 4; ++rg) {
        short8 a = *(const short8*)(Tb + swz(rg * 16 + l, kk * 64 + q * 16));
        acc[rg] = __builtin_amdgcn_mfma_f32_16x16x32_bf16(a, B2[kk], acc[rg], 0, 0, 0);
      }
    }
    const int m0 = t * M_BLK;
#pragma unroll
    for (int rg = 0; rg < 4; ++rg) {
#pragma unroll
      for (int i = 0; i < 4; ++i) {
        float v = acc[rg][i] + bias2;
        v = (v >= 0.f) ? v : 0.1f * v;
        out[(size_t)(m0 + rg * 16 + q * 4 + i) * 128 + wave * 16 + l] = v;
      }
    }
  };

  // ---- pipeline ----
  int ia, ib, ia2, ib2;
  short8 gy[2];
  float4 xu[4];

  LOAD_IDX(t0, ia, ib);
  LOAD_DATA(t0, ia, ib, gy, xu);
  WRITE_LDS(0, gy, xu);
  LOAD_IDX(t0 + 1, ia, ib);          // idx one tile ahead
  __syncthreads();

#pragma unroll
  for (int i = 0; i < ITERS; ++i) {
    if (i + 1 < ITERS) {
      LOAD_DATA(t0 + i + 1, ia, ib, gy, xu);   // issue loads; latency hides under GEMM
      if (i + 2 < ITERS) LOAD_IDX(t0 + i + 2, ia2, ib2);
    }
    GEMM_STORE(i & 1, t0 + i);
    if (i + 1 < ITERS) {
      WRITE_LDS((i + 1) & 1, gy, xu);          // waits on loads (after GEMM issued)
      ia = ia2; ib = ib2;
    }
    __syncthreads();
  }
}

extern "C" void kernel_launch(void* const* d_in, const int* in_sizes, int n_in,
                              void* d_out, int out_size, void* d_ws, size_t ws_size,
                              hipStream_t stream) {
  const float* x_down = (const float*)d_in[0];
  const float* x_up   = (const float*)d_in[1];
  const int*   up_idx = (const int*)d_in[2];
  const float* W_lin  = (const float*)d_in[3];
  const float* b_lin  = (const float*)d_in[4];
  const float* W_fus  = (const float*)d_in[5];
  const float* b_fus  = (const float*)d_in[6];
  float* out = (float*)d_out;

  // workspace layout: [0, 128 KiB) weight pack, [128 KiB, +16 MiB) y (bf16)
  __hip_bfloat16* pack = (__hip_bfloat16*)d_ws;
  __hip_bfloat16* y    = (__hip_bfloat16*)((char*)d_ws + 131072);

  repack_w<<<32, 256, 0, stream>>>(W_lin, W_fus, pack);
  mlp1_down<<<(BATCH * N_DOWN) / M_BLK, 512, 0, stream>>>(x_down, b_lin, pack, y);
  fused_cat<<<GRID_C, 512, 0, stream>>>(x_up, up_idx, y, b_fus, pack, out);
}